// Round 14
// baseline (200.498 us; speedup 1.0000x reference)
//
#include <hip/hip_runtime.h>

typedef unsigned short u16;
typedef _Float16 f16x8 __attribute__((ext_vector_type(8)));
typedef _Float16 f16x2 __attribute__((ext_vector_type(2)));
typedef float f32x4 __attribute__((ext_vector_type(4)));

// ---------- helpers ----------
__device__ __forceinline__ u16 f2h(float f){
  _Float16 h = (_Float16)f;                 // RNE f32->f16
  return __builtin_bit_cast(u16, h);
}

__device__ __forceinline__ void load_lds16(const void* g, void* l){
  __builtin_amdgcn_global_load_lds((const __attribute__((address_space(1))) void*)g,
                                   (__attribute__((address_space(3))) void*)l,
                                   16, 0, 0);
}

// ---------- zero ONLY the bevT halo (interior fully written by transpose) ----------
__global__ __launch_bounds__(256) void kv14_halo(u16* __restrict__ bevT)
{
  const int i = blockIdx.x * 256 + threadIdx.x;     // 8*804*8 = 51,456 16B-chunks
  if (i >= 8*804*8) return;
  const int b = i / (804*8);
  const int rem = i - b*(804*8);
  const int p = rem >> 3, c = rem & 7;
  int h, w;
  if (p < 202)      { h = 0;        w = p; }
  else if (p < 404) { h = 201;      w = p - 202; }
  else if (p < 604) { h = p - 403;  w = 0; }        // h = 1..200
  else              { h = p - 603;  w = 201; }
  const uint4 z = {0u,0u,0u,0u};
  *(uint4*)&bevT[(((size_t)b*202 + h)*202 + w)*64 + (c << 3)] = z;
}

// ---------- bev NCHW f32 -> padded NHWC f16 (8,202,202,64), interior only ----------
__global__ __launch_bounds__(256) void kv14_transpose(const float* __restrict__ bev,
                                                      u16* __restrict__ bevT)
{
  __shared__ float t[64][65];
  const int tid = threadIdx.x;
  const int bid = blockIdx.x;
  const int wc = bid & 3;
  const int h  = (bid >> 2) % 200;
  const int b  = bid / 800;
  const int w0 = wc << 6;

  const int wl = (tid & 15) << 2;
  const int cb = tid >> 4;
  if (w0 + wl < 200){
    #pragma unroll
    for (int r = 0; r < 4; ++r){
      const int c = cb + (r << 4);
      const float4 v = *(const float4*)&bev[(((size_t)b*64 + c)*200 + h)*200 + (w0 + wl)];
      t[c][wl] = v.x; t[c][wl+1] = v.y; t[c][wl+2] = v.z; t[c][wl+3] = v.w;
    }
  }
  __syncthreads();
  const int c0 = (tid & 7) << 3;
  #pragma unroll
  for (int j = 0; j < 2; ++j){
    const int wl2 = (tid >> 3) + (j << 5);
    if (w0 + wl2 < 200){
      unsigned r0 = (unsigned)f2h(t[c0+0][wl2]) | ((unsigned)f2h(t[c0+1][wl2]) << 16);
      unsigned r1 = (unsigned)f2h(t[c0+2][wl2]) | ((unsigned)f2h(t[c0+3][wl2]) << 16);
      unsigned r2 = (unsigned)f2h(t[c0+4][wl2]) | ((unsigned)f2h(t[c0+5][wl2]) << 16);
      unsigned r3 = (unsigned)f2h(t[c0+6][wl2]) | ((unsigned)f2h(t[c0+7][wl2]) << 16);
      uint4 o = {r0, r1, r2, r3};
      *(uint4*)&bevT[(((size_t)b*202 + h + 1)*202 + (w0 + wl2 + 1))*64 + c0] = o;
    }
  }
}

// ---------- weight prep: conv_w -> Wr[t9][d][c] f16 ; out_w -> owb[d][c] f16 ----------
__global__ __launch_bounds__(256) void kv14_prep(const float* __restrict__ conv_w,
                                                 const float* __restrict__ out_w,
                                                 u16* __restrict__ Wr,
                                                 u16* __restrict__ owb)
{
  const int i = blockIdx.x * 256 + threadIdx.x;
  if (i < 9*256*64){
    const int t9 = i / (256*64);
    const int rem = i - t9*(256*64);
    const int d = rem >> 6, c = rem & 63;
    Wr[i] = f2h(conv_w[(size_t)(d*64 + c)*9 + t9]);
  } else {
    const int j = i - 9*256*64;
    if (j < 65536) owb[j] = f2h(out_w[j]);
  }
}

// ---------- attention weights: softmax(queries @ attn_w^T + attn_b), f32 ----------
__global__ __launch_bounds__(256) void kv14_attw(const float* __restrict__ q,
                                                 const float* __restrict__ aw,
                                                 const float* __restrict__ ab,
                                                 float* __restrict__ attw)
{
  const int lane = threadIdx.x & 63;
  const int bq = blockIdx.x * 4 + (threadIdx.x >> 6);
  const float4 qv = *(const float4*)&q[(size_t)bq*256 + (lane << 2)];
  float lg[8];
  #pragma unroll
  for (int p = 0; p < 8; ++p){
    const float4 wv = *(const float4*)&aw[p*256 + (lane << 2)];
    float d = qv.x*wv.x + qv.y*wv.y + qv.z*wv.z + qv.w*wv.w;
    #pragma unroll
    for (int off = 32; off > 0; off >>= 1) d += __shfl_xor(d, off);
    lg[p] = d + ab[p];
  }
  float mx = lg[0];
  #pragma unroll
  for (int p = 1; p < 8; ++p) mx = fmaxf(mx, lg[p]);
  float sum = 0.f;
  #pragma unroll
  for (int p = 0; p < 8; ++p){ lg[p] = expf(lg[p] - mx); sum += lg[p]; }
  const float inv = 1.f / sum;
  if (lane == 0){
    float4 o0 = {lg[0]*inv, lg[1]*inv, lg[2]*inv, lg[3]*inv};
    float4 o1 = {lg[4]*inv, lg[5]*inv, lg[6]*inv, lg[7]*inv};
    *(float4*)&attw[(size_t)bq*8]     = o0;
    *(float4*)&attw[(size_t)bq*8 + 4] = o1;
  }
}

// ---------- conv3x3 + bias + relu, implicit GEMM M=320000 N=256 K=9*64 ----------
// v14 = R10/R13 dbuf with ONE barrier per tap (9 vs 18) and no explicit
// lgkmcnt drains. Schedule per tap t:
//   s_waitcnt vmcnt(0)   // my tap-t loads landed (issued iter t-1, full
//                        // compute section ago -> cheap)
//   s_barrier            // all waves waited first -> tap-t writes visible;
//                        // all waves' iter t-1 ds_reads consumed pre-arrival
//   sched_barrier(0)     // stage must not hoist above the barrier (rule #18)
//   STAGE(t+1 -> buf^1)  // loads fly under THIS tap's ds_read+MFMA
//   ds_read buf(t&1) + MFMA (setprio)
// Nothing crosses a barrier; hide-window identical to R10. Tail: __syncthreads
// before epilogue (t=8 buf0 reads vs epilogue writes).
__global__ __launch_bounds__(256) void kv14_conv(const u16* __restrict__ bevT,
                                                 const u16* __restrict__ Wr,
                                                 const float* __restrict__ conv_b,
                                                 u16* __restrict__ value)
{
  __shared__ __align__(16) u16 lds[32768];   // buf k @ k*16384: { A[128][64], B[128][64] }
  const int tid  = threadIdx.x;
  const int bid  = (int)(blockIdx.x & 7) * 625 + (int)(blockIdx.x >> 3);  // XCD-contiguous
  const int n0   = (bid & 1) << 7;
  const int m0   = (bid >> 1) << 7;
  const int lane = tid & 63;
  const int wv   = tid >> 6;
  const int wm   = (wv >> 1) << 6;
  const int wn   = (wv & 1) << 6;
  // inverse swizzle on the global source: LDS chunk (tid&7) of row (tid>>3)
  // receives global chunk (tid&7)^(row&7)
  const int c0   = (((tid & 7) ^ ((tid >> 3) & 7)) << 3);

  int baseA[4], baseB[4];
  #pragma unroll
  for (int i = 0; i < 4; ++i){
    const int m = m0 + (i << 5) + (tid >> 3);
    const int b = m / 40000;
    const int pix = m - b * 40000;
    const int h = pix / 200;
    const int w = pix - h * 200;
    baseA[i] = ((b*202 + h)*202 + w)*64 + c0;           // tap (0,0) in padded NHWC
    baseB[i] = (n0 + (i << 5) + (tid >> 3))*64 + c0;
  }

  const f32x4 z = {0.f, 0.f, 0.f, 0.f};
  f32x4 acc[4][4];
  #pragma unroll
  for (int mf = 0; mf < 4; ++mf)
    #pragma unroll
    for (int nf = 0; nf < 4; ++nf)
      acc[mf][nf] = z;

#define STAGE(buf, t9) do{                                                 \
    const int ky_ = (t9)/3;                                                \
    const int offA_ = (ky_*202 + ((t9) - ky_*3))*64;                       \
    const u16* ws_ = Wr + (t9)*16384;                                      \
    _Pragma("unroll")                                                      \
    for (int i_ = 0; i_ < 4; ++i_){                                        \
      load_lds16(bevT + baseA[i_] + offA_,                                 \
                 lds + (buf)*16384 + (i_ << 11) + (wv << 9));              \
      load_lds16(ws_ + baseB[i_],                                          \
                 lds + (buf)*16384 + 8192 + (i_ << 11) + (wv << 9));       \
    } }while(0)

  STAGE(0, 0);                               // tap-0's 8 loads in flight

  const int swz = lane & 7;                  // == row&7 for every fragment row
  #pragma unroll
  for (int t9 = 0; t9 < 9; ++t9){
    const int cur = t9 & 1;

    asm volatile("s_waitcnt vmcnt(0)" ::: "memory");     // my tap-t loads landed
    __builtin_amdgcn_s_barrier();            // all waves' tap-t writes visible
    __builtin_amdgcn_sched_barrier(0);       // keep stage below the barrier

    if (t9 < 8) STAGE(cur ^ 1, t9 + 1);      // next-tap loads fly under compute

    const u16* Lb = lds + cur*16384;
    f16x8 a_frag[2][4], b_frag[2][4];
    #pragma unroll
    for (int kh = 0; kh < 2; ++kh){
      const int c16 = (((kh << 2) + (lane >> 4)) ^ swz) << 3;
      #pragma unroll
      for (int f = 0; f < 4; ++f){
        a_frag[kh][f] = *(const f16x8*)&Lb[(wm + (f << 4) + (lane & 15))*64 + c16];
        b_frag[kh][f] = *(const f16x8*)&Lb[8192 + (wn + (f << 4) + (lane & 15))*64 + c16];
      }
    }
    __builtin_amdgcn_s_setprio(1);
    #pragma unroll
    for (int kh = 0; kh < 2; ++kh)
      #pragma unroll
      for (int mf = 0; mf < 4; ++mf)
        #pragma unroll
        for (int nf = 0; nf < 4; ++nf)
          acc[mf][nf] = __builtin_amdgcn_mfma_f32_16x16x32_f16(a_frag[kh][mf], b_frag[kh][nf], acc[mf][nf], 0, 0, 0);
    __builtin_amdgcn_s_setprio(0);
  }
#undef STAGE

  __syncthreads();                           // t=8 buf0 reads done before epilogue writes

  // epilogue: bias + relu -> f16 -> LDS [128][128] -> coalesced 16B stores
  #pragma unroll
  for (int nf = 0; nf < 4; ++nf){
    const int col = wn + (nf << 4) + (lane & 15);
    const float bias = conv_b[n0 + col];
    #pragma unroll
    for (int mf = 0; mf < 4; ++mf)
      #pragma unroll
      for (int rr = 0; rr < 4; ++rr){
        const int row = wm + (mf << 4) + ((lane >> 4) << 2) + rr;
        lds[row*128 + col] = f2h(fmaxf(acc[mf][nf][rr] + bias, 0.f));
      }
  }
  __syncthreads();
  #pragma unroll
  for (int it = 0; it < 8; ++it){
    const int idx = (it << 8) + tid;
    const int row = idx >> 4;
    const int ce  = (idx & 15) << 3;
    const f32x4 v = *(const f32x4*)&lds[row*128 + ce];
    *(f32x4*)&value[(size_t)(m0 + row)*256 + n0 + ce] = v;
  }
}

// ---------- bilinear sample + attention-weighted sum; s stored f16 ----------
// XCD-affine: qpair = (bid&7)*1024 + bid>>3 (bijective) -> batch k on XCD k.
__global__ __launch_bounds__(256) void kv14_sample(const float* __restrict__ traj,
                                                   const float* __restrict__ attw,
                                                   const u16* __restrict__ value,
                                                   u16* __restrict__ sbh)
{
  __shared__ int   pixs[2][32];
  __shared__ float wgts[2][32];
  const int tid  = threadIdx.x;
  const int half = tid >> 7;
  const int t    = tid & 127;
  const int qpair = (int)(blockIdx.x & 7) * 1024 + (int)(blockIdx.x >> 3);
  const int q    = (qpair << 1) + half;

  if (t < 8){
    const int p = t;
    const float ty = traj[((size_t)q*8 + p)*2 + 0];   // -> gy (grid = norm[..., ::-1])
    const float tx = traj[((size_t)q*8 + p)*2 + 1];   // -> gx
    float aw = attw[q*8 + p];
    const float gxn = tx / 30.f;
    const float gyn = ty / 30.f;
    if (!(gxn >= -1.f && gxn <= 1.f && gyn >= -1.f && gyn <= 1.f)) aw = 0.f;
    const float gx = (gxn + 1.f) * 0.5f * 199.f;
    const float gy = (gyn + 1.f) * 0.5f * 199.f;
    int x0 = (int)gx; x0 = min(max(x0, 0), 198);      // trunc-cast then clip, like reference
    int y0 = (int)gy; y0 = min(max(y0, 0), 198);
    const float wx = fminf(fmaxf(gx - (float)x0, 0.f), 1.f);
    const float wy = fminf(fmaxf(gy - (float)y0, 0.f), 1.f);
    const int base = y0*200 + x0;
    pixs[half][p*4+0] = base;       wgts[half][p*4+0] = aw*(1.f-wx)*(1.f-wy);
    pixs[half][p*4+1] = base+1;     wgts[half][p*4+1] = aw*wx*(1.f-wy);
    pixs[half][p*4+2] = base+200;   wgts[half][p*4+2] = aw*(1.f-wx)*wy;
    pixs[half][p*4+3] = base+201;   wgts[half][p*4+3] = aw*wx*wy;
  }
  __syncthreads();
  const size_t vbase = (size_t)(q >> 11) * 40000;     // b * H*W
  float a0 = 0.f, a1 = 0.f;
  #pragma unroll
  for (int i = 0; i < 32; ++i){
    const float w = wgts[half][i];
    const f16x2 pv = *(const f16x2*)&value[((vbase + pixs[half][i]) << 8) + (t << 1)];
    a0 = fmaf(w, (float)pv.x, a0);
    a1 = fmaf(w, (float)pv.y, a1);
  }
  const unsigned o = (unsigned)f2h(a0) | ((unsigned)f2h(a1) << 16);
  *(unsigned*)&sbh[((size_t)q << 8) + (t << 1)] = o;
}

// ---------- out = s @ out_w^T + out_b + queries : M=16384, N=256, K=256 (f16 MFMA) ----------
__global__ __launch_bounds__(256) void kv14_outgemm(const u16* __restrict__ sbh,
                                                    const u16* __restrict__ owb,
                                                    const float* __restrict__ out_b,
                                                    const float* __restrict__ queries,
                                                    float* __restrict__ outp)
{
  __shared__ __align__(16) u16 lds[16384];
  const int tid  = threadIdx.x;
  const int bid  = blockIdx.x;
  const int n0   = (bid & 1) << 7;
  const int m0   = (bid >> 1) << 7;
  const int lane = tid & 63;
  const int wv   = tid >> 6;
  const int wm   = (wv >> 1) << 6;
  const int wn   = (wv & 1) << 6;
  const int c0   = (tid & 7) << 3;

  int baseA[4], baseB[4];
  #pragma unroll
  for (int i = 0; i < 4; ++i){
    baseA[i] = (m0 + (i << 5) + (tid >> 3))*256 + c0;
    baseB[i] = (n0 + (i << 5) + (tid >> 3))*256 + c0;
  }
  const f32x4 z = {0.f, 0.f, 0.f, 0.f};
  f32x4 acc[4][4];
  #pragma unroll
  for (int mf = 0; mf < 4; ++mf)
    #pragma unroll
    for (int nf = 0; nf < 4; ++nf)
      acc[mf][nf] = z;

  for (int kk = 0; kk < 4; ++kk){
    #pragma unroll
    for (int i = 0; i < 4; ++i){
      load_lds16(sbh + baseA[i] + (kk << 6), lds + (i << 11) + (wv << 9));
      load_lds16(owb + baseB[i] + (kk << 6), lds + 8192 + (i << 11) + (wv << 9));
    }
    __syncthreads();

    f16x8 a_frag[2][4], b_frag[2][4];
    #pragma unroll
    for (int kh = 0; kh < 2; ++kh){
      const int kq = (kh << 5) + ((lane >> 4) << 3);
      #pragma unroll
      for (int f = 0; f < 4; ++f){
        a_frag[kh][f] = *(const f16x8*)&lds[(wm + (f << 4) + (lane & 15))*64 + kq];
        b_frag[kh][f] = *(const f16x8*)&lds[8192 + (wn + (f << 4) + (lane & 15))*64 + kq];
      }
    }
    #pragma unroll
    for (int kh = 0; kh < 2; ++kh)
      #pragma unroll
      for (int mf = 0; mf < 4; ++mf)
        #pragma unroll
        for (int nf = 0; nf < 4; ++nf)
          acc[mf][nf] = __builtin_amdgcn_mfma_f32_16x16x32_f16(a_frag[kh][mf], b_frag[kh][nf], acc[mf][nf], 0, 0, 0);
    __syncthreads();
  }

  #pragma unroll
  for (int nf = 0; nf < 4; ++nf){
    const int col = wn + (nf << 4) + (lane & 15);
    const float ob = out_b[n0 + col];
    #pragma unroll
    for (int mf = 0; mf < 4; ++mf)
      #pragma unroll
      for (int rr = 0; rr < 4; ++rr){
        const int row = wm + (mf << 4) + ((lane >> 4) << 2) + rr;
        const size_t off = (size_t)(m0 + row)*256 + n0 + col;
        outp[off] = acc[mf][nf][rr] + ob + queries[off];
      }
  }
}

// ---------- launch ----------
extern "C" void kernel_launch(void* const* d_in, const int* in_sizes, int n_in,
                              void* d_out, int out_size, void* d_ws, size_t ws_size,
                              hipStream_t stream)
{
  const float* queries = (const float*)d_in[0];
  const float* traj    = (const float*)d_in[1];
  const float* bev     = (const float*)d_in[2];
  const float* attn_w  = (const float*)d_in[3];
  const float* attn_b  = (const float*)d_in[4];
  const float* out_w   = (const float*)d_in[5];
  const float* out_b   = (const float*)d_in[6];
  const float* conv_w  = (const float*)d_in[7];
  const float* conv_b  = (const float*)d_in[8];
  float* outp = (float*)d_out;
  char* ws = (char*)d_ws;

  // workspace layout (bytes); bevT = 8*202*202*64*2 = 41,783,296 (exact)
  u16*   bevT  = (u16*)  (ws + 0);            // 41,783,296
  u16*   value = (u16*)  (ws + 41783296);     // 320000*256*2 = 163,840,000
  u16*   Wr    = (u16*)  (ws + 205623296);    // 9*256*64*2   = 294,912
  u16*   owb   = (u16*)  (ws + 205918208);    // 256*256*2    = 131,072
  float* attw  = (float*)(ws + 206049280);    // 16384*8*4    = 524,288
  u16*   sbh   = (u16*)  (ws + 206573568);    // 16384*256*2  = 8,388,608  (end 214,962,176)

  kv14_halo     <<<201,  256, 0, stream>>>(bevT);                  // zero halo only (823KB)
  kv14_transpose<<<6400, 256, 0, stream>>>(bev, bevT);
  kv14_prep     <<<832,  256, 0, stream>>>(conv_w, out_w, Wr, owb);
  kv14_attw     <<<4096, 256, 0, stream>>>(queries, attn_w, attn_b, attw);
  kv14_conv     <<<5000, 256, 0, stream>>>(bevT, Wr, conv_b, value);
  kv14_sample   <<<8192, 256, 0, stream>>>(traj, attw, value, sbh);
  kv14_outgemm  <<<256,  256, 0, stream>>>(sbh, owb, out_b, queries, outp);
}

// Round 15
// 197.569 us; speedup vs baseline: 1.0148x; 1.0148x over previous
//
#include <hip/hip_runtime.h>

typedef unsigned short u16;
typedef _Float16 f16x8 __attribute__((ext_vector_type(8)));
typedef _Float16 f16x2 __attribute__((ext_vector_type(2)));
typedef float f32x4 __attribute__((ext_vector_type(4)));

// ---------- helpers ----------
__device__ __forceinline__ u16 f2h(float f){
  _Float16 h = (_Float16)f;                 // RNE f32->f16
  return __builtin_bit_cast(u16, h);
}

__device__ __forceinline__ void load_lds16(const void* g, void* l){
  __builtin_amdgcn_global_load_lds((const __attribute__((address_space(1))) void*)g,
                                   (__attribute__((address_space(3))) void*)l,
                                   16, 0, 0);
}

// ---------- zero ONLY the bevT halo (interior fully written by transpose) ----------
__global__ __launch_bounds__(256) void kv15_halo(u16* __restrict__ bevT)
{
  const int i = blockIdx.x * 256 + threadIdx.x;     // 8*804*8 = 51,456 16B-chunks
  if (i >= 8*804*8) return;
  const int b = i / (804*8);
  const int rem = i - b*(804*8);
  const int p = rem >> 3, c = rem & 7;
  int h, w;
  if (p < 202)      { h = 0;        w = p; }
  else if (p < 404) { h = 201;      w = p - 202; }
  else if (p < 604) { h = p - 403;  w = 0; }        // h = 1..200
  else              { h = p - 603;  w = 201; }
  const uint4 z = {0u,0u,0u,0u};
  *(uint4*)&bevT[(((size_t)b*202 + h)*202 + w)*64 + (c << 3)] = z;
}

// ---------- bev NCHW f32 -> padded NHWC f16 (8,202,202,64), interior only ----------
__global__ __launch_bounds__(256) void kv15_transpose(const float* __restrict__ bev,
                                                      u16* __restrict__ bevT)
{
  __shared__ float t[64][65];
  const int tid = threadIdx.x;
  const int bid = blockIdx.x;
  const int wc = bid & 3;
  const int h  = (bid >> 2) % 200;
  const int b  = bid / 800;
  const int w0 = wc << 6;

  const int wl = (tid & 15) << 2;
  const int cb = tid >> 4;
  if (w0 + wl < 200){
    #pragma unroll
    for (int r = 0; r < 4; ++r){
      const int c = cb + (r << 4);
      const float4 v = *(const float4*)&bev[(((size_t)b*64 + c)*200 + h)*200 + (w0 + wl)];
      t[c][wl] = v.x; t[c][wl+1] = v.y; t[c][wl+2] = v.z; t[c][wl+3] = v.w;
    }
  }
  __syncthreads();
  const int c0 = (tid & 7) << 3;
  #pragma unroll
  for (int j = 0; j < 2; ++j){
    const int wl2 = (tid >> 3) + (j << 5);
    if (w0 + wl2 < 200){
      unsigned r0 = (unsigned)f2h(t[c0+0][wl2]) | ((unsigned)f2h(t[c0+1][wl2]) << 16);
      unsigned r1 = (unsigned)f2h(t[c0+2][wl2]) | ((unsigned)f2h(t[c0+3][wl2]) << 16);
      unsigned r2 = (unsigned)f2h(t[c0+4][wl2]) | ((unsigned)f2h(t[c0+5][wl2]) << 16);
      unsigned r3 = (unsigned)f2h(t[c0+6][wl2]) | ((unsigned)f2h(t[c0+7][wl2]) << 16);
      uint4 o = {r0, r1, r2, r3};
      *(uint4*)&bevT[(((size_t)b*202 + h + 1)*202 + (w0 + wl2 + 1))*64 + c0] = o;
    }
  }
}

// ---------- weight prep: conv_w -> Wr[t9][d][c] f16 ; out_w -> owb[d][c] f16 ----------
__global__ __launch_bounds__(256) void kv15_prep(const float* __restrict__ conv_w,
                                                 const float* __restrict__ out_w,
                                                 u16* __restrict__ Wr,
                                                 u16* __restrict__ owb)
{
  const int i = blockIdx.x * 256 + threadIdx.x;
  if (i < 9*256*64){
    const int t9 = i / (256*64);
    const int rem = i - t9*(256*64);
    const int d = rem >> 6, c = rem & 63;
    Wr[i] = f2h(conv_w[(size_t)(d*64 + c)*9 + t9]);
  } else {
    const int j = i - 9*256*64;
    if (j < 65536) owb[j] = f2h(out_w[j]);
  }
}

// ---------- attention weights: softmax(queries @ attn_w^T + attn_b), f32 ----------
__global__ __launch_bounds__(256) void kv15_attw(const float* __restrict__ q,
                                                 const float* __restrict__ aw,
                                                 const float* __restrict__ ab,
                                                 float* __restrict__ attw)
{
  const int lane = threadIdx.x & 63;
  const int bq = blockIdx.x * 4 + (threadIdx.x >> 6);
  const float4 qv = *(const float4*)&q[(size_t)bq*256 + (lane << 2)];
  float lg[8];
  #pragma unroll
  for (int p = 0; p < 8; ++p){
    const float4 wv = *(const float4*)&aw[p*256 + (lane << 2)];
    float d = qv.x*wv.x + qv.y*wv.y + qv.z*wv.z + qv.w*wv.w;
    #pragma unroll
    for (int off = 32; off > 0; off >>= 1) d += __shfl_xor(d, off);
    lg[p] = d + ab[p];
  }
  float mx = lg[0];
  #pragma unroll
  for (int p = 1; p < 8; ++p) mx = fmaxf(mx, lg[p]);
  float sum = 0.f;
  #pragma unroll
  for (int p = 0; p < 8; ++p){ lg[p] = expf(lg[p] - mx); sum += lg[p]; }
  const float inv = 1.f / sum;
  if (lane == 0){
    float4 o0 = {lg[0]*inv, lg[1]*inv, lg[2]*inv, lg[3]*inv};
    float4 o1 = {lg[4]*inv, lg[5]*inv, lg[6]*inv, lg[7]*inv};
    *(float4*)&attw[(size_t)bq*8]     = o0;
    *(float4*)&attw[(size_t)bq*8 + 4] = o1;
  }
}

// ---------- conv3x3 + bias + relu, implicit GEMM M=320000 N=256 K=9*64 ----------
// R10/R13 exactly (measured plateau 113±1us across three sync variants):
// counted-vmcnt dbuf. Per tap t: STAGE(t+1 -> buf^1); vmcnt(8) (tap t's 8
// loads retired, t+1's stay in flight); s_barrier (cross-wave visibility:
// every wave's vmcnt wait precedes it); ds_read+MFMA; lgkmcnt(0); s_barrier.
__global__ __launch_bounds__(256) void kv15_conv(const u16* __restrict__ bevT,
                                                 const u16* __restrict__ Wr,
                                                 const float* __restrict__ conv_b,
                                                 u16* __restrict__ value)
{
  __shared__ __align__(16) u16 lds[32768];   // buf k @ k*16384: { A[128][64], B[128][64] }
  const int tid  = threadIdx.x;
  const int bid  = (int)(blockIdx.x & 7) * 625 + (int)(blockIdx.x >> 3);  // XCD-contiguous
  const int n0   = (bid & 1) << 7;
  const int m0   = (bid >> 1) << 7;
  const int lane = tid & 63;
  const int wv   = tid >> 6;
  const int wm   = (wv >> 1) << 6;
  const int wn   = (wv & 1) << 6;
  // inverse swizzle on the global source: LDS chunk (tid&7) of row (tid>>3)
  // receives global chunk (tid&7)^(row&7)
  const int c0   = (((tid & 7) ^ ((tid >> 3) & 7)) << 3);

  int baseA[4], baseB[4];
  #pragma unroll
  for (int i = 0; i < 4; ++i){
    const int m = m0 + (i << 5) + (tid >> 3);
    const int b = m / 40000;
    const int pix = m - b * 40000;
    const int h = pix / 200;
    const int w = pix - h * 200;
    baseA[i] = ((b*202 + h)*202 + w)*64 + c0;           // tap (0,0) in padded NHWC
    baseB[i] = (n0 + (i << 5) + (tid >> 3))*64 + c0;
  }

  const f32x4 z = {0.f, 0.f, 0.f, 0.f};
  f32x4 acc[4][4];
  #pragma unroll
  for (int mf = 0; mf < 4; ++mf)
    #pragma unroll
    for (int nf = 0; nf < 4; ++nf)
      acc[mf][nf] = z;

#define STAGE(buf, t9) do{                                                 \
    const int ky_ = (t9)/3;                                                \
    const int offA_ = (ky_*202 + ((t9) - ky_*3))*64;                       \
    const u16* ws_ = Wr + (t9)*16384;                                      \
    _Pragma("unroll")                                                      \
    for (int i_ = 0; i_ < 4; ++i_){                                        \
      load_lds16(bevT + baseA[i_] + offA_,                                 \
                 lds + (buf)*16384 + (i_ << 11) + (wv << 9));              \
      load_lds16(ws_ + baseB[i_],                                          \
                 lds + (buf)*16384 + 8192 + (i_ << 11) + (wv << 9));       \
    } }while(0)

  STAGE(0, 0);                               // 8 loads in flight

  const int swz = lane & 7;                  // == row&7 for every fragment row
  #pragma unroll
  for (int t9 = 0; t9 < 9; ++t9){
    const int cur = t9 & 1;
    if (t9 < 8) STAGE(cur ^ 1, t9 + 1);      // +8 loads (next tap), stay in flight

    if (t9 < 8) asm volatile("s_waitcnt vmcnt(8)" ::: "memory");   // tap t landed
    else        asm volatile("s_waitcnt vmcnt(0)" ::: "memory");   // tail drain
    __builtin_amdgcn_s_barrier();            // all waves' tap-t writes visible

    const u16* Lb = lds + cur*16384;
    f16x8 a_frag[2][4], b_frag[2][4];
    #pragma unroll
    for (int kh = 0; kh < 2; ++kh){
      const int c16 = (((kh << 2) + (lane >> 4)) ^ swz) << 3;
      #pragma unroll
      for (int f = 0; f < 4; ++f){
        a_frag[kh][f] = *(const f16x8*)&Lb[(wm + (f << 4) + (lane & 15))*64 + c16];
        b_frag[kh][f] = *(const f16x8*)&Lb[8192 + (wn + (f << 4) + (lane & 15))*64 + c16];
      }
    }
    __builtin_amdgcn_s_setprio(1);
    #pragma unroll
    for (int kh = 0; kh < 2; ++kh)
      #pragma unroll
      for (int mf = 0; mf < 4; ++mf)
        #pragma unroll
        for (int nf = 0; nf < 4; ++nf)
          acc[mf][nf] = __builtin_amdgcn_mfma_f32_16x16x32_f16(a_frag[kh][mf], b_frag[kh][nf], acc[mf][nf], 0, 0, 0);
    __builtin_amdgcn_s_setprio(0);

    asm volatile("s_waitcnt lgkmcnt(0)" ::: "memory");   // my reads of Lb done
    __builtin_amdgcn_s_barrier();            // safe to overwrite Lb next iter
  }
#undef STAGE

  // epilogue: bias + relu -> f16 -> LDS [128][128] -> coalesced 16B stores
  #pragma unroll
  for (int nf = 0; nf < 4; ++nf){
    const int col = wn + (nf << 4) + (lane & 15);
    const float bias = conv_b[n0 + col];
    #pragma unroll
    for (int mf = 0; mf < 4; ++mf)
      #pragma unroll
      for (int rr = 0; rr < 4; ++rr){
        const int row = wm + (mf << 4) + ((lane >> 4) << 2) + rr;
        lds[row*128 + col] = f2h(fmaxf(acc[mf][nf][rr] + bias, 0.f));
      }
  }
  __syncthreads();
  #pragma unroll
  for (int it = 0; it < 8; ++it){
    const int idx = (it << 8) + tid;
    const int row = idx >> 4;
    const int ce  = (idx & 15) << 3;
    const f32x4 v = *(const f32x4*)&lds[row*128 + ce];
    *(f32x4*)&value[(size_t)(m0 + row)*256 + n0 + ce] = v;
  }
}

// ---------- bilinear sample + attention-weighted sum; s stored f16 ----------
// XCD-affine: qpair = (bid&7)*1024 + bid>>3 (bijective) -> batch k on XCD k,
// per-XCD L2 sees one 20.5MB value slice instead of all 164MB.
__global__ __launch_bounds__(256) void kv15_sample(const float* __restrict__ traj,
                                                   const float* __restrict__ attw,
                                                   const u16* __restrict__ value,
                                                   u16* __restrict__ sbh)
{
  __shared__ int   pixs[2][32];
  __shared__ float wgts[2][32];
  const int tid  = threadIdx.x;
  const int half = tid >> 7;
  const int t    = tid & 127;
  const int qpair = (int)(blockIdx.x & 7) * 1024 + (int)(blockIdx.x >> 3);
  const int q    = (qpair << 1) + half;

  if (t < 8){
    const int p = t;
    const float ty = traj[((size_t)q*8 + p)*2 + 0];   // -> gy (grid = norm[..., ::-1])
    const float tx = traj[((size_t)q*8 + p)*2 + 1];   // -> gx
    float aw = attw[q*8 + p];
    const float gxn = tx / 30.f;
    const float gyn = ty / 30.f;
    if (!(gxn >= -1.f && gxn <= 1.f && gyn >= -1.f && gyn <= 1.f)) aw = 0.f;
    const float gx = (gxn + 1.f) * 0.5f * 199.f;
    const float gy = (gyn + 1.f) * 0.5f * 199.f;
    int x0 = (int)gx; x0 = min(max(x0, 0), 198);      // trunc-cast then clip, like reference
    int y0 = (int)gy; y0 = min(max(y0, 0), 198);
    const float wx = fminf(fmaxf(gx - (float)x0, 0.f), 1.f);
    const float wy = fminf(fmaxf(gy - (float)y0, 0.f), 1.f);
    const int base = y0*200 + x0;
    pixs[half][p*4+0] = base;       wgts[half][p*4+0] = aw*(1.f-wx)*(1.f-wy);
    pixs[half][p*4+1] = base+1;     wgts[half][p*4+1] = aw*wx*(1.f-wy);
    pixs[half][p*4+2] = base+200;   wgts[half][p*4+2] = aw*(1.f-wx)*wy;
    pixs[half][p*4+3] = base+201;   wgts[half][p*4+3] = aw*wx*wy;
  }
  __syncthreads();
  const size_t vbase = (size_t)(q >> 11) * 40000;     // b * H*W
  float a0 = 0.f, a1 = 0.f;
  #pragma unroll
  for (int i = 0; i < 32; ++i){
    const float w = wgts[half][i];
    const f16x2 pv = *(const f16x2*)&value[((vbase + pixs[half][i]) << 8) + (t << 1)];
    a0 = fmaf(w, (float)pv.x, a0);
    a1 = fmaf(w, (float)pv.y, a1);
  }
  const unsigned o = (unsigned)f2h(a0) | ((unsigned)f2h(a1) << 16);
  *(unsigned*)&sbh[((size_t)q << 8) + (t << 1)] = o;
}

// ---------- out = s @ out_w^T + out_b + queries : M=16384, N=256, K=256 (f16 MFMA) ----------
__global__ __launch_bounds__(256) void kv15_outgemm(const u16* __restrict__ sbh,
                                                    const u16* __restrict__ owb,
                                                    const float* __restrict__ out_b,
                                                    const float* __restrict__ queries,
                                                    float* __restrict__ outp)
{
  __shared__ __align__(16) u16 lds[16384];
  const int tid  = threadIdx.x;
  const int bid  = blockIdx.x;
  const int n0   = (bid & 1) << 7;
  const int m0   = (bid >> 1) << 7;
  const int lane = tid & 63;
  const int wv   = tid >> 6;
  const int wm   = (wv >> 1) << 6;
  const int wn   = (wv & 1) << 6;
  const int c0   = (tid & 7) << 3;

  int baseA[4], baseB[4];
  #pragma unroll
  for (int i = 0; i < 4; ++i){
    baseA[i] = (m0 + (i << 5) + (tid >> 3))*256 + c0;
    baseB[i] = (n0 + (i << 5) + (tid >> 3))*256 + c0;
  }
  const f32x4 z = {0.f, 0.f, 0.f, 0.f};
  f32x4 acc[4][4];
  #pragma unroll
  for (int mf = 0; mf < 4; ++mf)
    #pragma unroll
    for (int nf = 0; nf < 4; ++nf)
      acc[mf][nf] = z;

  for (int kk = 0; kk < 4; ++kk){
    #pragma unroll
    for (int i = 0; i < 4; ++i){
      load_lds16(sbh + baseA[i] + (kk << 6), lds + (i << 11) + (wv << 9));
      load_lds16(owb + baseB[i] + (kk << 6), lds + 8192 + (i << 11) + (wv << 9));
    }
    __syncthreads();

    f16x8 a_frag[2][4], b_frag[2][4];
    #pragma unroll
    for (int kh = 0; kh < 2; ++kh){
      const int kq = (kh << 5) + ((lane >> 4) << 3);
      #pragma unroll
      for (int f = 0; f < 4; ++f){
        a_frag[kh][f] = *(const f16x8*)&lds[(wm + (f << 4) + (lane & 15))*64 + kq];
        b_frag[kh][f] = *(const f16x8*)&lds[8192 + (wn + (f << 4) + (lane & 15))*64 + kq];
      }
    }
    #pragma unroll
    for (int kh = 0; kh < 2; ++kh)
      #pragma unroll
      for (int mf = 0; mf < 4; ++mf)
        #pragma unroll
        for (int nf = 0; nf < 4; ++nf)
          acc[mf][nf] = __builtin_amdgcn_mfma_f32_16x16x32_f16(a_frag[kh][mf], b_frag[kh][nf], acc[mf][nf], 0, 0, 0);
    __syncthreads();
  }

  #pragma unroll
  for (int nf = 0; nf < 4; ++nf){
    const int col = wn + (nf << 4) + (lane & 15);
    const float ob = out_b[n0 + col];
    #pragma unroll
    for (int mf = 0; mf < 4; ++mf)
      #pragma unroll
      for (int rr = 0; rr < 4; ++rr){
        const int row = wm + (mf << 4) + ((lane >> 4) << 2) + rr;
        const size_t off = (size_t)(m0 + row)*256 + n0 + col;
        outp[off] = acc[mf][nf][rr] + ob + queries[off];
      }
  }
}

// ---------- launch ----------
extern "C" void kernel_launch(void* const* d_in, const int* in_sizes, int n_in,
                              void* d_out, int out_size, void* d_ws, size_t ws_size,
                              hipStream_t stream)
{
  const float* queries = (const float*)d_in[0];
  const float* traj    = (const float*)d_in[1];
  const float* bev     = (const float*)d_in[2];
  const float* attn_w  = (const float*)d_in[3];
  const float* attn_b  = (const float*)d_in[4];
  const float* out_w   = (const float*)d_in[5];
  const float* out_b   = (const float*)d_in[6];
  const float* conv_w  = (const float*)d_in[7];
  const float* conv_b  = (const float*)d_in[8];
  float* outp = (float*)d_out;
  char* ws = (char*)d_ws;

  // workspace layout (bytes); bevT = 8*202*202*64*2 = 41,783,296 (exact)
  u16*   bevT  = (u16*)  (ws + 0);            // 41,783,296
  u16*   value = (u16*)  (ws + 41783296);     // 320000*256*2 = 163,840,000
  u16*   Wr    = (u16*)  (ws + 205623296);    // 9*256*64*2   = 294,912
  u16*   owb   = (u16*)  (ws + 205918208);    // 256*256*2    = 131,072
  float* attw  = (float*)(ws + 206049280);    // 16384*8*4    = 524,288
  u16*   sbh   = (u16*)  (ws + 206573568);    // 16384*256*2  = 8,388,608  (end 214,962,176)

  kv15_halo     <<<201,  256, 0, stream>>>(bevT);                  // zero halo only (823KB)
  kv15_transpose<<<6400, 256, 0, stream>>>(bev, bevT);
  kv15_prep     <<<832,  256, 0, stream>>>(conv_w, out_w, Wr, owb);
  kv15_attw     <<<4096, 256, 0, stream>>>(queries, attn_w, attn_b, attw);
  kv15_conv     <<<5000, 256, 0, stream>>>(bevT, Wr, conv_b, value);
  kv15_sample   <<<8192, 256, 0, stream>>>(traj, attw, value, sbh);
  kv15_outgemm  <<<256,  256, 0, stream>>>(sbh, owb, out_b, queries, outp);
}